// Round 1
// baseline (155.272 us; speedup 1.0000x reference)
//
#include <hip/hip_runtime.h>

// 5x5 box filter, zero padding, fp32 in/out, 8192x8192.
// Memory-bound: floor = (256 MiB read + 256 MiB write) / 6.3 TB/s ~= 85 us.

constexpr int H = 8192;
constexpr int W = 8192;
constexpr int ROWS = 32;   // output rows per block (vertical over-fetch 36/32)
constexpr int TPB  = 256;  // threads per block; each thread does 4 columns

typedef float f4 __attribute__((ext_vector_type(4)));
typedef f4 __attribute__((aligned(4))) f4u;   // allow 8B-aligned vector loads

__global__ __launch_bounds__(TPB)
void box5_kernel(const float* __restrict__ in, float* __restrict__ out) {
    const int c0 = blockIdx.x * (TPB * 4) + threadIdx.x * 4;  // first of 4 output cols
    const int y0 = blockIdx.y * ROWS;                          // first output row
    // Interior iff window [c0-2, c0+5] fully inside [0, W)
    const bool interior = (c0 >= 2) && (c0 + 5 < W);

    float h[5][4];  // ring buffer of horizontal 5-sums for 5 consecutive rows

    auto load_h = [&](int y, float* hh) {
        if ((unsigned)y >= (unsigned)H) {
            hh[0] = hh[1] = hh[2] = hh[3] = 0.0f;
            return;
        }
        const float* rp = in + (size_t)y * W;
        float w[8];
        if (interior) {
            // c0 is a multiple of 4 -> (c0-2) and (c0+2) are 8B-aligned
            f4 a = *(const f4u*)(rp + c0 - 2);
            f4 b = *(const f4u*)(rp + c0 + 2);
            w[0] = a[0]; w[1] = a[1]; w[2] = a[2]; w[3] = a[3];
            w[4] = b[0]; w[5] = b[1]; w[6] = b[2]; w[7] = b[3];
        } else {
            #pragma unroll
            for (int k = 0; k < 8; ++k) {
                int idx = c0 - 2 + k;
                w[k] = ((unsigned)idx < (unsigned)W) ? rp[idx] : 0.0f;
            }
        }
        #pragma unroll
        for (int j = 0; j < 4; ++j)
            hh[j] = ((w[j] + w[j + 1]) + (w[j + 2] + w[j + 3])) + w[j + 4];
    };

    // Prologue: rows y0-2 .. y0+1 into ring slots 0..3
    #pragma unroll
    for (int i = 0; i < 4; ++i)
        load_h(y0 - 2 + i, h[i]);

    const float inv25 = 1.0f / 25.0f;

    #pragma unroll
    for (int i = 0; i < ROWS; ++i) {
        const int y = y0 + i;
        load_h(y + 2, h[(i + 4) % 5]);  // compile-time index (full unroll)
        f4 o;
        #pragma unroll
        for (int j = 0; j < 4; ++j) {
            o[j] = (((h[0][j] + h[1][j]) + (h[2][j] + h[3][j])) + h[4][j]) * inv25;
        }
        *(f4*)(out + (size_t)y * W + c0) = o;  // c0 mult of 4 -> 16B aligned
    }
}

extern "C" void kernel_launch(void* const* d_in, const int* in_sizes, int n_in,
                              void* d_out, int out_size, void* d_ws, size_t ws_size,
                              hipStream_t stream) {
    const float* in = (const float*)d_in[0];
    // d_in[1] is the uniform 5x5 kernel = ones/25; folded into inv25 constant.
    float* out = (float*)d_out;
    dim3 grid(W / (TPB * 4), H / ROWS);  // (8, 256) = 2048 blocks
    box5_kernel<<<grid, dim3(TPB), 0, stream>>>(in, out);
}